// Round 9
// baseline (177.338 us; speedup 1.0000x reference)
//
#include <hip/hip_runtime.h>
#include <hip/hip_fp16.h>
#include <math.h>

#define N_NODES 100000
#define N_EDGES 1600000
#define F_IN 100
#define F_H 32

#define BKT_SHIFT 7
#define BKT_C 128                       // nodes per bucket
#define NBK 782                         // ceil(N_NODES / BKT_C)
#define BKT_CAP 2560                    // fixed bucket capacity; mean 2046, sigma 45

// binfill: TILE/NBK = avg bucket-run length ~10.5 -- must stay >~10 for
// coalesced packed writes (2048-tile regression: run=2.6 -> +30us)
// NOTE (r1): NO global degree atomics (~+85us). NOTE (r3): NO grid.sync
// persistent merge. NOTE (r4): work stealing neutral. NOTE (r5): NO column
// planes -- gathers must stay 4 lanes x 16B = one full 64B line per edge.
// NOTE (r6): NO degree-sorted groups (rank-loop cost > divergence win).
// NOTE (r7): NO split-half groups (serial tail dominated). r8: esrc padded
// to x8 with a zero-row index -> all gather batches full. r9: ping-pong
// register double-buffer -> loads of batch i+1 issue before batch i is
// accumulated (counted vmcnt instead of per-batch drain).
#define BF_B 1024
#define BF_EPT 8
#define BF_TILE 8192                    // BF_B * BF_EPT
#define BF_GRID 196                     // ceil(N_EDGES / BF_TILE)

#define XW_ROWS 256
#define XW_S2 51                        // LDS row stride in half2 units (102 halfs)
#define XW_NT 391                       // ceil(N_NODES / XW_ROWS)

#define FUSE_GRID 512                   // uniform 2 blocks/CU at 58.6 KB LDS
#define SM_BYTES 58624                  // union: binfill 58604 / xw 52224

#define AG_B 512
#define AG_ESRC 3200                    // padded capacity: max cnum 2210 + 128*7
#define AG_EPT 5                        // ceil(BKT_CAP / AG_B)
#define ZROW N_NODES                    // dummy all-zero h2 row for pad slots

// ---------------------------------------------- fused roles + work stealing
// (verified round-4 body, unchanged)
__global__ __launch_bounds__(BF_B) void fused1_kernel(
        const int* __restrict__ src, const int* __restrict__ dst,
        int* __restrict__ gcursor, int* __restrict__ xwctr,
        unsigned* __restrict__ packed,
        const float* __restrict__ x, const float* __restrict__ W,
        float* __restrict__ h2f) {
    __shared__ char smraw[SM_BYTES] __attribute__((aligned(16)));
    __shared__ int stile;
    int t = threadIdx.x;
    if (blockIdx.x < BF_GRID) {
        int* cnt = (int*)smraw;                     // NBK
        int* lbase = cnt + NBK;                     // NBK
        int* gbase = lbase + NBK;                   // NBK
        int* wsums = gbase + NBK;                   // 16
        int* ptot = wsums + 16;                     // 1
        unsigned* stage = (unsigned*)(ptot + 1);    // BF_TILE (32 KB)
        unsigned short* stageB = (unsigned short*)(stage + BF_TILE);  // 16 KB
        long base = (long)blockIdx.x * BF_TILE;
        for (int i = t; i < NBK; i += BF_B) cnt[i] = 0;
        __syncthreads();
        int myb[BF_EPT]; int mypos[BF_EPT]; unsigned mypk[BF_EPT];
#pragma unroll
        for (int k = 0; k < BF_EPT; k++) {
            long e = base + t + (long)k * BF_B;      // coalesced
            myb[k] = -1;
            if (e < N_EDGES) {
                int d = dst[e];
                int sI = src[e];
                int b = d >> BKT_SHIFT;
                myb[k] = b;
                mypk[k] = (unsigned)sI | ((unsigned)(d & (BKT_C - 1)) << 17);
                mypos[k] = atomicAdd(&cnt[b], 1);
            }
        }
        __syncthreads();
        if (t < NBK && cnt[t] > 0)
            gbase[t] = t * BKT_CAP + atomicAdd(&gcursor[t], cnt[t]);
        int lane = t & 63, w = t >> 6;
        int v = (t < NBK) ? cnt[t] : 0;
        int sc = v;
#pragma unroll
        for (int off = 1; off < 64; off <<= 1) {
            int xx = __shfl_up(sc, off, 64);
            if (lane >= off) sc += xx;
        }
        if (lane == 63) wsums[w] = sc;
        __syncthreads();
        int pre = 0;
#pragma unroll
        for (int u = 0; u < 16; u++) pre += (u < w) ? wsums[u] : 0;
        int incl = sc + pre;
        if (t < NBK) lbase[t] = incl - v;
        if (t == BF_B - 1) ptot[0] = incl;
        __syncthreads();
#pragma unroll
        for (int k = 0; k < BF_EPT; k++) {
            if (myb[k] >= 0) {
                int p = lbase[myb[k]] + mypos[k];
                stage[p] = mypk[k];
                stageB[p] = (unsigned short)myb[k];
            }
        }
        __syncthreads();
        int T = ptot[0];
        for (int i = t; i < T; i += BF_B) {          // bucket runs -> contiguous
            int b = stageB[i];
            packed[gbase[b] + (i - lbase[b])] = stage[i];
        }
    }
    // ---------------- xw steal loop (all blocks) ----------------
    __half2* xs = (__half2*)smraw;                   // 256 * XW_S2 half2 (52.2 KB)
    for (;;) {
        if (t == 0) stile = atomicAdd(xwctr, 1);
        __syncthreads();
        int tb = stile;
        if (tb >= XW_NT) break;
        int rbase = tb * XW_ROWS;
        int rows = min(XW_ROWS, N_NODES - rbase);
        int total = rows * F_IN;                     // multiple of 4
        const float4* gx4 = (const float4*)(x + (long)rbase * F_IN);
        for (int i4 = t; i4 < (total >> 2); i4 += BF_B) {
            float4 v = gx4[i4];                      // coalesced
            int i = i4 << 2;
            int r = i / F_IN;
            int k = i - r * F_IN;
            __half2* p = xs + r * XW_S2 + (k >> 1);
            p[0] = __floats2half2_rn(v.x, v.y);
            p[1] = __floats2half2_rn(v.z, v.w);
        }
        __syncthreads();
        int r = t & (XW_ROWS - 1);
        int colbase = __builtin_amdgcn_readfirstlane((t >> 8) << 3);
        if (r < rows) {
            const float* Wp = W + colbase;
            float acc[8];
#pragma unroll
            for (int j = 0; j < 8; j++) acc[j] = 0.f;
            const __half2* xr = xs + r * XW_S2;
#pragma unroll 5
            for (int k2 = 0; k2 < F_IN / 2; k2++) {
                float2 xv = __half22float2(xr[k2]);  // 1 ds_read_b32 / 16 FMA
#pragma unroll
                for (int j = 0; j < 8; j++)
                    acc[j] = fmaf(xv.y, Wp[(2 * k2 + 1) * F_H + j],
                                  fmaf(xv.x, Wp[(2 * k2) * F_H + j], acc[j]));
            }
            float4* dst4 = (float4*)(h2f + (long)(rbase + r) * F_H + colbase);
            dst4[0] = make_float4(acc[0], acc[1], acc[2], acc[3]);
            dst4[1] = make_float4(acc[4], acc[5], acc[6], acc[7]);
        }
        __syncthreads();
    }
}

// ---------------------------------------------- per-bucket: degree histogram ->
// dinv per row -> h2(fp16) = h2f * dinv (row-major, verified round-2/4 body);
// block 0 also writes the all-zero pad row at index ZROW.
__global__ __launch_bounds__(256) void scale_kernel(
        const int* __restrict__ blen, const unsigned* __restrict__ packed,
        const float* __restrict__ h2f, __half* __restrict__ h2) {
    __shared__ int cnt[BKT_C];
    __shared__ float sdv[BKT_C];
    int t = threadIdx.x;
    int b = blockIdx.x;
    if (t < BKT_C) cnt[t] = 0;
    __syncthreads();
    int beg = b * BKT_CAP, end = beg + blen[b];
    for (int i = beg + t; i < end; i += 256)
        atomicAdd(&cnt[(packed[i] >> 17) & (BKT_C - 1)], 1);
    __syncthreads();
    if (t < BKT_C) sdv[t] = rsqrtf((float)cnt[t] + 1.0f);
    __syncthreads();
    int rbase = b << BKT_SHIFT;
    int rows = min(BKT_C, N_NODES - rbase);
    const float4* src4 = (const float4*)(h2f + (long)rbase * F_H);
    float2* dst2 = (float2*)h2;                      // 4 halves per float2 slot
    if (b == 0 && t < 8)                             // zero pad row (64 B)
        dst2[(long)ZROW * 8 + t] = make_float2(0.f, 0.f);
    for (int i4 = t; i4 < rows * 8; i4 += 256) {     // rows * 32 floats / 4
        float4 v = src4[i4];                         // coalesced 16 B
        float dv = sdv[i4 >> 3];
        float2 o;
        __half2* oh = (__half2*)&o;
        oh[0] = __floats2half2_rn(v.x * dv, v.y * dv);
        oh[1] = __floats2half2_rn(v.z * dv, v.w * dv);
        dst2[(long)rbase * 8 + i4] = o;              // coalesced 8 B
    }
}

// ---------------------------------------------- per-bucket: LDS counting sort
// into x8-PADDED segments (pad slots = ZROW) -> PIPELINED gather (ping-pong
// A/B register sets; batch i+1's loads issue before batch i accumulates ->
// counted vmcnt, 16 batches-worth in flight) -> fused MLP + log_softmax
__global__ __launch_bounds__(AG_B) void agg_kernel(
        const int* __restrict__ blen, const unsigned* __restrict__ packed,
        const __half* __restrict__ h2,
        const float* __restrict__ bc,
        const float* __restrict__ W1, const float* __restrict__ b1,
        const float* __restrict__ W2, const float* __restrict__ b2,
        const float* __restrict__ W3, const float* __restrict__ b3,
        float* __restrict__ out) {
    __shared__ float accL[BKT_C * 33];           // 16.9 KB; written once per node
    __shared__ int esrc[AG_ESRC];                // 12.8 KB padded node-sorted src
    __shared__ int cnt[BKT_C];
    __shared__ int pstart[BKT_C];                // padded segment start per node
    __shared__ int wsum;
    __shared__ int ptotT;                        // total padded entries
    __shared__ float sbc[32], sW1[512], sb1[16], sW2[128], sb2[8], sW3[80], sb3[10];
    int t = threadIdx.x;
    if (t < 32) sbc[t] = bc[t];
    if (t < 512) sW1[t] = W1[t];
    if (t < 16) sb1[t] = b1[t];
    if (t < 128) sW2[t] = W2[t];
    if (t < 8) sb2[t] = b2[t];
    if (t < 80) sW3[t] = W3[t];
    if (t < 10) sb3[t] = b3[t];

    int b = blockIdx.x;
    int beg = b * BKT_CAP;
    int cnum = blen[b];                          // <= 2210 guaranteed
    if (t < BKT_C) cnt[t] = 0;
    __syncthreads();
    unsigned pk[AG_EPT]; int pos[AG_EPT];
#pragma unroll
    for (int k = 0; k < AG_EPT; k++) {
        int idx = t + k * AG_B;                  // coalesced
        pk[k] = 0xFFFFFFFFu;
        if (idx < cnum) {
            unsigned p = packed[beg + idx];
            pk[k] = p;
            pos[k] = atomicAdd(&cnt[(p >> 17) & (BKT_C - 1)], 1);
        }
    }
    __syncthreads();
    // inclusive scan of PADDED counts ((cnt+7)&~7) -> pstart per node
    {
        int lane = t & 63;
        int v = 0;
        if (t < BKT_C) {
            v = (cnt[t] + 7) & ~7;
#pragma unroll
            for (int off = 1; off < 64; off <<= 1) {
                int xx = __shfl_up(v, off, 64);
                if (lane >= off) v += xx;
            }
            if (t == 63) wsum = v;
        }
        __syncthreads();
        if (t < BKT_C) {
            if (t >= 64) v += wsum;
            pstart[t] = v - ((cnt[t] + 7) & ~7);
            if (t == BKT_C - 1) ptotT = v;
        }
    }
    __syncthreads();
    // pre-fill pad slots with the zero-row id, then scatter real edges
    for (int i = t; i < ptotT; i += AG_B) esrc[i] = ZROW;
    __syncthreads();
#pragma unroll
    for (int k = 0; k < AG_EPT; k++) {
        if (pk[k] != 0xFFFFFFFFu) {
            int lid = (pk[k] >> 17) & (BKT_C - 1);
            esrc[pstart[lid] + pos[k]] = (int)(pk[k] & 0x1FFFF);
        }
    }
    __syncthreads();
    // gather: group g (= t>>2) owns node g; lane l (= t&3) owns cols 8l..8l+7
    // (16 B -> 4 lanes cover one 64 B line per edge). Segments are x8-padded;
    // ping-pong A/B register sets pipeline loads across batches.
    {
        int g = t >> 2, l = t & 3;
        const float4* h2o = (const float4*)h2;   // row = 4 float4 (8 halfs each)
        int e = pstart[g];
        int nb = ((cnt[g] + 7) & ~7) >> 3;       // number of 8-batches
        float a0 = 0.f, a1 = 0.f, a2 = 0.f, a3 = 0.f;
        float a4 = 0.f, a5 = 0.f, a6 = 0.f, a7 = 0.f;
        float4 A0, A1, A2, A3, A4, A5, A6, A7;
        float4 B0, B1, B2, B3, B4, B5, B6, B7;

#define LD(Q, EE) { \
        int s0_ = esrc[EE], s1_ = esrc[(EE)+1], s2_ = esrc[(EE)+2]; \
        int s3_ = esrc[(EE)+3], s4_ = esrc[(EE)+4], s5_ = esrc[(EE)+5]; \
        int s6_ = esrc[(EE)+6], s7_ = esrc[(EE)+7]; \
        Q##0 = h2o[s0_ * 4 + l]; Q##1 = h2o[s1_ * 4 + l]; \
        Q##2 = h2o[s2_ * 4 + l]; Q##3 = h2o[s3_ * 4 + l]; \
        Q##4 = h2o[s4_ * 4 + l]; Q##5 = h2o[s5_ * 4 + l]; \
        Q##6 = h2o[s6_ * 4 + l]; Q##7 = h2o[s7_ * 4 + l]; }

#define AC1(qq) { const __half2* hp_ = (const __half2*)&(qq); \
        float2 f0_ = __half22float2(hp_[0]); \
        float2 f1_ = __half22float2(hp_[1]); \
        float2 f2_ = __half22float2(hp_[2]); \
        float2 f3_ = __half22float2(hp_[3]); \
        a0 += f0_.x; a1 += f0_.y; a2 += f1_.x; a3 += f1_.y; \
        a4 += f2_.x; a5 += f2_.y; a6 += f3_.x; a7 += f3_.y; }

#define AC(Q) { AC1(Q##0) AC1(Q##1) AC1(Q##2) AC1(Q##3) \
                AC1(Q##4) AC1(Q##5) AC1(Q##6) AC1(Q##7) }

        if (nb > 0) {
            LD(A, e); e += 8;
            int rem = nb - 1;
            while (rem >= 2) {                   // steady state: 16 in flight
                LD(B, e); e += 8;
                AC(A);                           // waits only on A (counted vmcnt)
                LD(A, e); e += 8;
                AC(B);
                rem -= 2;
            }
            if (rem == 1) { LD(B, e); AC(A); AC(B); }
            else { AC(A); }
        }
#undef LD
#undef AC1
#undef AC
        float* ap = accL + g * 33 + 8 * l;
        ap[0] = a0; ap[1] = a1; ap[2] = a2; ap[3] = a3;
        ap[4] = a4; ap[5] = a5; ap[6] = a6; ap[7] = a7;
    }
    __syncthreads();

    // epilogue: threads 0..127 each finish one node; dinv[dst] from the local
    // histogram (cnt[t] == full in-degree of node n)
    int n = (b << BKT_SHIFT) + t;
    if (t < BKT_C && n < N_NODES) {
        float dv = rsqrtf((float)cnt[t] + 1.0f);
        const __half2* h2v = (const __half2*)h2;
        float a[32];
#pragma unroll
        for (int q = 0; q < 16; q++) {
            float2 hv = __half22float2(h2v[n * 16 + q]);   // self-loop (pre-scaled)
            a[2*q]   = fmaxf((accL[t * 33 + 2*q]   + hv.x) * dv + sbc[2*q],   0.f);
            a[2*q+1] = fmaxf((accL[t * 33 + 2*q+1] + hv.y) * dv + sbc[2*q+1], 0.f);
        }
        float t1[16];
#pragma unroll
        for (int j = 0; j < 16; j++) {
            float s = sb1[j];
            for (int k = 0; k < 32; k++) s += a[k] * sW1[k * 16 + j];
            t1[j] = fmaxf(s, 0.f);
        }
        float t2[8];
#pragma unroll
        for (int j = 0; j < 8; j++) {
            float s = sb2[j];
            for (int k = 0; k < 16; k++) s += t1[k] * sW2[k * 8 + j];
            t2[j] = fmaxf(s, 0.f);
        }
        float t3[10];
#pragma unroll
        for (int j = 0; j < 10; j++) {
            float s = sb3[j];
            for (int k = 0; k < 8; k++) s += t2[k] * sW3[k * 10 + j];
            t3[j] = s;
        }
        float m = t3[0];
#pragma unroll
        for (int j = 1; j < 10; j++) m = fmaxf(m, t3[j]);
        float se = 0.f;
#pragma unroll
        for (int j = 0; j < 10; j++) se += expf(t3[j] - m);
        float lse = logf(se) + m;
        float* op = out + (long)n * 10;
#pragma unroll
        for (int j = 0; j < 10; j++) op[j] = t3[j] - lse;
    }
}

extern "C" void kernel_launch(void* const* d_in, const int* in_sizes, int n_in,
                              void* d_out, int out_size, void* d_ws, size_t ws_size,
                              hipStream_t stream) {
    const float* x  = (const float*)d_in[0];
    const int*   ei = (const int*)d_in[1];  // [2, E] int32
    const float* Wc = (const float*)d_in[3];
    const float* bc = (const float*)d_in[4];
    const float* W1 = (const float*)d_in[5];
    const float* b1 = (const float*)d_in[6];
    const float* W2 = (const float*)d_in[7];
    const float* b2 = (const float*)d_in[8];
    const float* W3 = (const float*)d_in[9];
    const float* b3 = (const float*)d_in[10];
    float* out = (float*)d_out;

    // h2 has ONE extra zero row (index N_NODES) for gather padding
    __half*   h2      = (__half*)d_ws;                          // (N+1)*32 fp16
    unsigned* packed  = (unsigned*)((char*)d_ws
                         + (long)(N_NODES + 1) * F_H * 2);      // NBK*CAP (8 MB)
    float*    h2f     = (float*)(packed + (long)NBK * BKT_CAP); // N*32 fp32 (12.8 MB)
    int*      gcursor = (int*)(h2f + (long)N_NODES * F_H);      // NBK
    int*      xwctr   = gcursor + NBK;                          // 1 (steal counter)

    const int* srcp = ei;
    const int* dstp = ei + N_EDGES;

    hipMemsetAsync(gcursor, 0, (NBK + 1) * sizeof(int), stream);
    fused1_kernel<<<FUSE_GRID, BF_B, 0, stream>>>(srcp, dstp, gcursor, xwctr,
                                                  packed, x, Wc, h2f);
    scale_kernel<<<NBK, 256, 0, stream>>>(gcursor, packed, h2f, h2);
    agg_kernel<<<NBK, AG_B, 0, stream>>>(gcursor, packed, h2, bc, W1, b1,
                                         W2, b2, W3, b3, out);
}

// Round 10
// 176.880 us; speedup vs baseline: 1.0026x; 1.0026x over previous
//
#include <hip/hip_runtime.h>
#include <hip/hip_fp16.h>
#include <math.h>

#define N_NODES 100000
#define N_EDGES 1600000
#define F_IN 100
#define F_H 32

#define BKT_SHIFT 7
#define BKT_C 128                       // nodes per bucket
#define NBK 782                         // ceil(N_NODES / BKT_C)
#define BKT_CAP 2560                    // fixed bucket capacity; mean 2046, sigma 45

// binfill: r10 halves the tile (8192 -> 4096): per-block serial path (read ->
// LDS atomics -> scan -> scatter -> write, 8 barrier phases) halves; 391+121
// blocks still = one co-resident round of 512. The old "2048-tile +30us"
// data point had BF_GRID=782 > 512 slots (a second dispatch round) -- this
// probes whether run-length (10.5 -> 5.2) or grid-overflow caused it.
// NOTE (r1): NO global degree atomics (~+85us). NOTE (r3): NO grid.sync
// persistent merge. NOTE (r4): work stealing neutral but kept (free balance).
// NOTE (r5): NO column planes -- gathers stay 4 lanes x 16B = one 64B line.
// NOTE (r6): NO degree-sorted groups. NOTE (r7): NO split-half groups.
// r8: esrc x8-padded with zero-row -> no serial tail (timed best 170.1).
// NOTE (r9): NO ping-pong gather pipeline -- agg is MSHR-bound (~44us wall),
// depth doesn't help; timed 177.
#define BF_B 1024
#define BF_EPT 4
#define BF_TILE 4096                    // BF_B * BF_EPT
#define BF_GRID 391                     // ceil(N_EDGES / BF_TILE)

#define XW_ROWS 256
#define XW_S2 51                        // LDS row stride in half2 units (102 halfs)
#define XW_NT 391                       // ceil(N_NODES / XW_ROWS)

#define FUSE_GRID 512                   // 391 binfill + 121 xw-steal; 2 blk/CU
#define SM_BYTES 52224                  // union: xw 52224 / binfill ~34028

#define AG_B 512
#define AG_ESRC 3200                    // padded capacity: max cnum 2210 + 128*7
#define AG_EPT 5                        // ceil(BKT_CAP / AG_B)
#define ZROW N_NODES                    // dummy all-zero h2 row for pad slots

// ---------------------------------------------- fused roles + work stealing
__global__ __launch_bounds__(BF_B) void fused1_kernel(
        const int* __restrict__ src, const int* __restrict__ dst,
        int* __restrict__ gcursor, int* __restrict__ xwctr,
        unsigned* __restrict__ packed,
        const float* __restrict__ x, const float* __restrict__ W,
        float* __restrict__ h2f) {
    __shared__ char smraw[SM_BYTES] __attribute__((aligned(16)));
    __shared__ int stile;
    int t = threadIdx.x;
    if (blockIdx.x < BF_GRID) {
        int* cnt = (int*)smraw;                     // NBK
        int* lbase = cnt + NBK;                     // NBK
        int* gbase = lbase + NBK;                   // NBK
        int* wsums = gbase + NBK;                   // 16
        int* ptot = wsums + 16;                     // 1
        unsigned* stage = (unsigned*)(ptot + 1);    // BF_TILE (16 KB)
        unsigned short* stageB = (unsigned short*)(stage + BF_TILE);  // 8 KB
        long base = (long)blockIdx.x * BF_TILE;
        for (int i = t; i < NBK; i += BF_B) cnt[i] = 0;
        __syncthreads();
        int myb[BF_EPT]; int mypos[BF_EPT]; unsigned mypk[BF_EPT];
#pragma unroll
        for (int k = 0; k < BF_EPT; k++) {
            long e = base + t + (long)k * BF_B;      // coalesced
            myb[k] = -1;
            if (e < N_EDGES) {
                int d = dst[e];
                int sI = src[e];
                int b = d >> BKT_SHIFT;
                myb[k] = b;
                mypk[k] = (unsigned)sI | ((unsigned)(d & (BKT_C - 1)) << 17);
                mypos[k] = atomicAdd(&cnt[b], 1);
            }
        }
        __syncthreads();
        if (t < NBK && cnt[t] > 0)
            gbase[t] = t * BKT_CAP + atomicAdd(&gcursor[t], cnt[t]);
        int lane = t & 63, w = t >> 6;
        int v = (t < NBK) ? cnt[t] : 0;
        int sc = v;
#pragma unroll
        for (int off = 1; off < 64; off <<= 1) {
            int xx = __shfl_up(sc, off, 64);
            if (lane >= off) sc += xx;
        }
        if (lane == 63) wsums[w] = sc;
        __syncthreads();
        int pre = 0;
#pragma unroll
        for (int u = 0; u < 16; u++) pre += (u < w) ? wsums[u] : 0;
        int incl = sc + pre;
        if (t < NBK) lbase[t] = incl - v;
        if (t == BF_B - 1) ptot[0] = incl;
        __syncthreads();
#pragma unroll
        for (int k = 0; k < BF_EPT; k++) {
            if (myb[k] >= 0) {
                int p = lbase[myb[k]] + mypos[k];
                stage[p] = mypk[k];
                stageB[p] = (unsigned short)myb[k];
            }
        }
        __syncthreads();
        int T = ptot[0];
        for (int i = t; i < T; i += BF_B) {          // bucket runs -> contiguous
            int b = stageB[i];
            packed[gbase[b] + (i - lbase[b])] = stage[i];
        }
    }
    // ---------------- xw steal loop (all blocks) ----------------
    __half2* xs = (__half2*)smraw;                   // 256 * XW_S2 half2 (52.2 KB)
    for (;;) {
        if (t == 0) stile = atomicAdd(xwctr, 1);
        __syncthreads();
        int tb = stile;
        if (tb >= XW_NT) break;
        int rbase = tb * XW_ROWS;
        int rows = min(XW_ROWS, N_NODES - rbase);
        int total = rows * F_IN;                     // multiple of 4
        const float4* gx4 = (const float4*)(x + (long)rbase * F_IN);
        for (int i4 = t; i4 < (total >> 2); i4 += BF_B) {
            float4 v = gx4[i4];                      // coalesced
            int i = i4 << 2;
            int r = i / F_IN;
            int k = i - r * F_IN;
            __half2* p = xs + r * XW_S2 + (k >> 1);
            p[0] = __floats2half2_rn(v.x, v.y);
            p[1] = __floats2half2_rn(v.z, v.w);
        }
        __syncthreads();
        int r = t & (XW_ROWS - 1);
        int colbase = __builtin_amdgcn_readfirstlane((t >> 8) << 3);
        if (r < rows) {
            const float* Wp = W + colbase;
            float acc[8];
#pragma unroll
            for (int j = 0; j < 8; j++) acc[j] = 0.f;
            const __half2* xr = xs + r * XW_S2;
#pragma unroll 5
            for (int k2 = 0; k2 < F_IN / 2; k2++) {
                float2 xv = __half22float2(xr[k2]);  // 1 ds_read_b32 / 16 FMA
#pragma unroll
                for (int j = 0; j < 8; j++)
                    acc[j] = fmaf(xv.y, Wp[(2 * k2 + 1) * F_H + j],
                                  fmaf(xv.x, Wp[(2 * k2) * F_H + j], acc[j]));
            }
            float4* dst4 = (float4*)(h2f + (long)(rbase + r) * F_H + colbase);
            dst4[0] = make_float4(acc[0], acc[1], acc[2], acc[3]);
            dst4[1] = make_float4(acc[4], acc[5], acc[6], acc[7]);
        }
        __syncthreads();
    }
}

// ---------------------------------------------- per-bucket: degree histogram ->
// dinv per row -> h2(fp16) = h2f * dinv (row-major, verified round-2/4 body);
// block 0 also writes the all-zero pad row at index ZROW.
__global__ __launch_bounds__(256) void scale_kernel(
        const int* __restrict__ blen, const unsigned* __restrict__ packed,
        const float* __restrict__ h2f, __half* __restrict__ h2) {
    __shared__ int cnt[BKT_C];
    __shared__ float sdv[BKT_C];
    int t = threadIdx.x;
    int b = blockIdx.x;
    if (t < BKT_C) cnt[t] = 0;
    __syncthreads();
    int beg = b * BKT_CAP, end = beg + blen[b];
    for (int i = beg + t; i < end; i += 256)
        atomicAdd(&cnt[(packed[i] >> 17) & (BKT_C - 1)], 1);
    __syncthreads();
    if (t < BKT_C) sdv[t] = rsqrtf((float)cnt[t] + 1.0f);
    __syncthreads();
    int rbase = b << BKT_SHIFT;
    int rows = min(BKT_C, N_NODES - rbase);
    const float4* src4 = (const float4*)(h2f + (long)rbase * F_H);
    float2* dst2 = (float2*)h2;                      // 4 halves per float2 slot
    if (b == 0 && t < 8)                             // zero pad row (64 B)
        dst2[(long)ZROW * 8 + t] = make_float2(0.f, 0.f);
    for (int i4 = t; i4 < rows * 8; i4 += 256) {     // rows * 32 floats / 4
        float4 v = src4[i4];                         // coalesced 16 B
        float dv = sdv[i4 >> 3];
        float2 o;
        __half2* oh = (__half2*)&o;
        oh[0] = __floats2half2_rn(v.x * dv, v.y * dv);
        oh[1] = __floats2half2_rn(v.z * dv, v.w * dv);
        dst2[(long)rbase * 8 + i4] = o;              // coalesced 8 B
    }
}

// ---------------------------------------------- per-bucket: LDS counting sort
// into x8-PADDED segments (pad slots = ZROW) -> full-batch gathers, no tail
// (r8 timed-best body) -> fused MLP + log_softmax
__global__ __launch_bounds__(AG_B) void agg_kernel(
        const int* __restrict__ blen, const unsigned* __restrict__ packed,
        const __half* __restrict__ h2,
        const float* __restrict__ bc,
        const float* __restrict__ W1, const float* __restrict__ b1,
        const float* __restrict__ W2, const float* __restrict__ b2,
        const float* __restrict__ W3, const float* __restrict__ b3,
        float* __restrict__ out) {
    __shared__ float accL[BKT_C * 33];           // 16.9 KB; written once per node
    __shared__ int esrc[AG_ESRC];                // 12.8 KB padded node-sorted src
    __shared__ int cnt[BKT_C];
    __shared__ int pstart[BKT_C];                // padded segment start per node
    __shared__ int wsum;
    __shared__ int ptotT;                        // total padded entries
    __shared__ float sbc[32], sW1[512], sb1[16], sW2[128], sb2[8], sW3[80], sb3[10];
    int t = threadIdx.x;
    if (t < 32) sbc[t] = bc[t];
    if (t < 512) sW1[t] = W1[t];
    if (t < 16) sb1[t] = b1[t];
    if (t < 128) sW2[t] = W2[t];
    if (t < 8) sb2[t] = b2[t];
    if (t < 80) sW3[t] = W3[t];
    if (t < 10) sb3[t] = b3[t];

    int b = blockIdx.x;
    int beg = b * BKT_CAP;
    int cnum = blen[b];                          // <= 2210 guaranteed
    if (t < BKT_C) cnt[t] = 0;
    __syncthreads();
    unsigned pk[AG_EPT]; int pos[AG_EPT];
#pragma unroll
    for (int k = 0; k < AG_EPT; k++) {
        int idx = t + k * AG_B;                  // coalesced
        pk[k] = 0xFFFFFFFFu;
        if (idx < cnum) {
            unsigned p = packed[beg + idx];
            pk[k] = p;
            pos[k] = atomicAdd(&cnt[(p >> 17) & (BKT_C - 1)], 1);
        }
    }
    __syncthreads();
    // inclusive scan of PADDED counts ((cnt+7)&~7) -> pstart per node
    {
        int lane = t & 63;
        int v = 0;
        if (t < BKT_C) {
            v = (cnt[t] + 7) & ~7;
#pragma unroll
            for (int off = 1; off < 64; off <<= 1) {
                int xx = __shfl_up(v, off, 64);
                if (lane >= off) v += xx;
            }
            if (t == 63) wsum = v;
        }
        __syncthreads();
        if (t < BKT_C) {
            if (t >= 64) v += wsum;
            pstart[t] = v - ((cnt[t] + 7) & ~7);
            if (t == BKT_C - 1) ptotT = v;
        }
    }
    __syncthreads();
    // pre-fill pad slots with the zero-row id, then scatter real edges
    for (int i = t; i < ptotT; i += AG_B) esrc[i] = ZROW;
    __syncthreads();
#pragma unroll
    for (int k = 0; k < AG_EPT; k++) {
        if (pk[k] != 0xFFFFFFFFu) {
            int lid = (pk[k] >> 17) & (BKT_C - 1);
            esrc[pstart[lid] + pos[k]] = (int)(pk[k] & 0x1FFFF);
        }
    }
    __syncthreads();
    // gather: group g (= t>>2) owns node g; lane l (= t&3) owns cols 8l..8l+7
    // (16 B -> 4 lanes cover one 64 B line per edge). Segment length is a
    // multiple of 8 -> every iteration issues 8 independent loads (pad slots
    // hit the L1-resident zero row and add exact +0).
    {
        int g = t >> 2, l = t & 3;
        const float4* h2o = (const float4*)h2;   // row = 4 float4 (8 halfs each)
        int e = pstart[g];
        int eend = e + ((cnt[g] + 7) & ~7);
        float a0 = 0.f, a1 = 0.f, a2 = 0.f, a3 = 0.f;
        float a4 = 0.f, a5 = 0.f, a6 = 0.f, a7 = 0.f;
        for (; e < eend; e += 8) {               // 8 independent 16 B gathers
            int s0 = esrc[e], s1 = esrc[e+1], s2 = esrc[e+2], s3 = esrc[e+3];
            int s4 = esrc[e+4], s5 = esrc[e+5], s6 = esrc[e+6], s7 = esrc[e+7];
            float4 q0 = h2o[s0 * 4 + l];
            float4 q1 = h2o[s1 * 4 + l];
            float4 q2 = h2o[s2 * 4 + l];
            float4 q3 = h2o[s3 * 4 + l];
            float4 q4 = h2o[s4 * 4 + l];
            float4 q5 = h2o[s5 * 4 + l];
            float4 q6 = h2o[s6 * 4 + l];
            float4 q7 = h2o[s7 * 4 + l];
#pragma unroll
            for (int u = 0; u < 8; u++) {
                float4 q = (u == 0) ? q0 : (u == 1) ? q1 : (u == 2) ? q2 :
                           (u == 3) ? q3 : (u == 4) ? q4 : (u == 5) ? q5 :
                           (u == 6) ? q6 : q7;
                const __half2* hp = (const __half2*)&q;
                float2 f0 = __half22float2(hp[0]);
                float2 f1 = __half22float2(hp[1]);
                float2 f2 = __half22float2(hp[2]);
                float2 f3 = __half22float2(hp[3]);
                a0 += f0.x; a1 += f0.y; a2 += f1.x; a3 += f1.y;
                a4 += f2.x; a5 += f2.y; a6 += f3.x; a7 += f3.y;
            }
        }
        float* ap = accL + g * 33 + 8 * l;
        ap[0] = a0; ap[1] = a1; ap[2] = a2; ap[3] = a3;
        ap[4] = a4; ap[5] = a5; ap[6] = a6; ap[7] = a7;
    }
    __syncthreads();

    // epilogue: threads 0..127 each finish one node; dinv[dst] from the local
    // histogram (cnt[t] == full in-degree of node n)
    int n = (b << BKT_SHIFT) + t;
    if (t < BKT_C && n < N_NODES) {
        float dv = rsqrtf((float)cnt[t] + 1.0f);
        const __half2* h2v = (const __half2*)h2;
        float a[32];
#pragma unroll
        for (int q = 0; q < 16; q++) {
            float2 hv = __half22float2(h2v[n * 16 + q]);   // self-loop (pre-scaled)
            a[2*q]   = fmaxf((accL[t * 33 + 2*q]   + hv.x) * dv + sbc[2*q],   0.f);
            a[2*q+1] = fmaxf((accL[t * 33 + 2*q+1] + hv.y) * dv + sbc[2*q+1], 0.f);
        }
        float t1[16];
#pragma unroll
        for (int j = 0; j < 16; j++) {
            float s = sb1[j];
            for (int k = 0; k < 32; k++) s += a[k] * sW1[k * 16 + j];
            t1[j] = fmaxf(s, 0.f);
        }
        float t2[8];
#pragma unroll
        for (int j = 0; j < 8; j++) {
            float s = sb2[j];
            for (int k = 0; k < 16; k++) s += t1[k] * sW2[k * 8 + j];
            t2[j] = fmaxf(s, 0.f);
        }
        float t3[10];
#pragma unroll
        for (int j = 0; j < 10; j++) {
            float s = sb3[j];
            for (int k = 0; k < 8; k++) s += t2[k] * sW3[k * 10 + j];
            t3[j] = s;
        }
        float m = t3[0];
#pragma unroll
        for (int j = 1; j < 10; j++) m = fmaxf(m, t3[j]);
        float se = 0.f;
#pragma unroll
        for (int j = 0; j < 10; j++) se += expf(t3[j] - m);
        float lse = logf(se) + m;
        float* op = out + (long)n * 10;
#pragma unroll
        for (int j = 0; j < 10; j++) op[j] = t3[j] - lse;
    }
}

extern "C" void kernel_launch(void* const* d_in, const int* in_sizes, int n_in,
                              void* d_out, int out_size, void* d_ws, size_t ws_size,
                              hipStream_t stream) {
    const float* x  = (const float*)d_in[0];
    const int*   ei = (const int*)d_in[1];  // [2, E] int32
    const float* Wc = (const float*)d_in[3];
    const float* bc = (const float*)d_in[4];
    const float* W1 = (const float*)d_in[5];
    const float* b1 = (const float*)d_in[6];
    const float* W2 = (const float*)d_in[7];
    const float* b2 = (const float*)d_in[8];
    const float* W3 = (const float*)d_in[9];
    const float* b3 = (const float*)d_in[10];
    float* out = (float*)d_out;

    // h2 has ONE extra zero row (index N_NODES) for gather padding
    __half*   h2      = (__half*)d_ws;                          // (N+1)*32 fp16
    unsigned* packed  = (unsigned*)((char*)d_ws
                         + (long)(N_NODES + 1) * F_H * 2);      // NBK*CAP (8 MB)
    float*    h2f     = (float*)(packed + (long)NBK * BKT_CAP); // N*32 fp32 (12.8 MB)
    int*      gcursor = (int*)(h2f + (long)N_NODES * F_H);      // NBK
    int*      xwctr   = gcursor + NBK;                          // 1 (steal counter)

    const int* srcp = ei;
    const int* dstp = ei + N_EDGES;

    hipMemsetAsync(gcursor, 0, (NBK + 1) * sizeof(int), stream);
    fused1_kernel<<<FUSE_GRID, BF_B, 0, stream>>>(srcp, dstp, gcursor, xwctr,
                                                  packed, x, Wc, h2f);
    scale_kernel<<<NBK, 256, 0, stream>>>(gcursor, packed, h2f, h2);
    agg_kernel<<<NBK, AG_B, 0, stream>>>(gcursor, packed, h2, bc, W1, b1,
                                         W2, b2, W3, b3, out);
}

// Round 11
// 169.534 us; speedup vs baseline: 1.0460x; 1.0433x over previous
//
#include <hip/hip_runtime.h>
#include <hip/hip_fp16.h>
#include <math.h>

#define N_NODES 100000
#define N_EDGES 1600000
#define F_IN 100
#define F_H 32

#define BKT_SHIFT 7
#define BKT_C 128                       // nodes per bucket
#define NBK 782                         // ceil(N_NODES / BKT_C)
#define BKT_CAP 2560                    // fixed bucket capacity; mean 2046, sigma 45

// binfill: TILE/NBK = avg bucket-run length ~10.5 -- must stay >~10 for
// coalesced packed writes. CONFIRMED r10: TILE 4096 (run 5.2) = +7us; the
// historical 2048-tile +30us was run-length, not grid overflow. Keep 8192.
// NOTE (r1): NO global degree atomics (~+85us). NOTE (r3): NO grid.sync
// persistent merge. NOTE (r4): work stealing neutral but kept (free balance).
// NOTE (r5): NO column planes -- gathers stay 4 lanes x 16B = one 64B line.
// NOTE (r6): NO degree-sorted groups. NOTE (r7): NO split-half groups.
// r8: esrc x8-padded with zero-row -> no serial tail (timed best 170.1).
// NOTE (r9): NO ping-pong gather pipeline -- agg is MSHR-bound (~44us wall),
// depth doesn't help. This file == the r8 timed-best configuration.
#define BF_B 1024
#define BF_EPT 8
#define BF_TILE 8192                    // BF_B * BF_EPT
#define BF_GRID 196                     // ceil(N_EDGES / BF_TILE)

#define XW_ROWS 256
#define XW_S2 51                        // LDS row stride in half2 units (102 halfs)
#define XW_NT 391                       // ceil(N_NODES / XW_ROWS)

#define FUSE_GRID 512                   // uniform 2 blocks/CU at 58.6 KB LDS
#define SM_BYTES 58624                  // union: binfill 58604 / xw 52224

#define AG_B 512
#define AG_ESRC 3200                    // padded capacity: max cnum 2210 + 128*7
#define AG_EPT 5                        // ceil(BKT_CAP / AG_B)
#define ZROW N_NODES                    // dummy all-zero h2 row for pad slots

// ---------------------------------------------- fused roles + work stealing
__global__ __launch_bounds__(BF_B) void fused1_kernel(
        const int* __restrict__ src, const int* __restrict__ dst,
        int* __restrict__ gcursor, int* __restrict__ xwctr,
        unsigned* __restrict__ packed,
        const float* __restrict__ x, const float* __restrict__ W,
        float* __restrict__ h2f) {
    __shared__ char smraw[SM_BYTES] __attribute__((aligned(16)));
    __shared__ int stile;
    int t = threadIdx.x;
    if (blockIdx.x < BF_GRID) {
        int* cnt = (int*)smraw;                     // NBK
        int* lbase = cnt + NBK;                     // NBK
        int* gbase = lbase + NBK;                   // NBK
        int* wsums = gbase + NBK;                   // 16
        int* ptot = wsums + 16;                     // 1
        unsigned* stage = (unsigned*)(ptot + 1);    // BF_TILE (32 KB)
        unsigned short* stageB = (unsigned short*)(stage + BF_TILE);  // 16 KB
        long base = (long)blockIdx.x * BF_TILE;
        for (int i = t; i < NBK; i += BF_B) cnt[i] = 0;
        __syncthreads();
        int myb[BF_EPT]; int mypos[BF_EPT]; unsigned mypk[BF_EPT];
#pragma unroll
        for (int k = 0; k < BF_EPT; k++) {
            long e = base + t + (long)k * BF_B;      // coalesced
            myb[k] = -1;
            if (e < N_EDGES) {
                int d = dst[e];
                int sI = src[e];
                int b = d >> BKT_SHIFT;
                myb[k] = b;
                mypk[k] = (unsigned)sI | ((unsigned)(d & (BKT_C - 1)) << 17);
                mypos[k] = atomicAdd(&cnt[b], 1);
            }
        }
        __syncthreads();
        if (t < NBK && cnt[t] > 0)
            gbase[t] = t * BKT_CAP + atomicAdd(&gcursor[t], cnt[t]);
        int lane = t & 63, w = t >> 6;
        int v = (t < NBK) ? cnt[t] : 0;
        int sc = v;
#pragma unroll
        for (int off = 1; off < 64; off <<= 1) {
            int xx = __shfl_up(sc, off, 64);
            if (lane >= off) sc += xx;
        }
        if (lane == 63) wsums[w] = sc;
        __syncthreads();
        int pre = 0;
#pragma unroll
        for (int u = 0; u < 16; u++) pre += (u < w) ? wsums[u] : 0;
        int incl = sc + pre;
        if (t < NBK) lbase[t] = incl - v;
        if (t == BF_B - 1) ptot[0] = incl;
        __syncthreads();
#pragma unroll
        for (int k = 0; k < BF_EPT; k++) {
            if (myb[k] >= 0) {
                int p = lbase[myb[k]] + mypos[k];
                stage[p] = mypk[k];
                stageB[p] = (unsigned short)myb[k];
            }
        }
        __syncthreads();
        int T = ptot[0];
        for (int i = t; i < T; i += BF_B) {          // bucket runs -> contiguous
            int b = stageB[i];
            packed[gbase[b] + (i - lbase[b])] = stage[i];
        }
    }
    // ---------------- xw steal loop (all blocks) ----------------
    __half2* xs = (__half2*)smraw;                   // 256 * XW_S2 half2 (52.2 KB)
    for (;;) {
        if (t == 0) stile = atomicAdd(xwctr, 1);
        __syncthreads();
        int tb = stile;
        if (tb >= XW_NT) break;
        int rbase = tb * XW_ROWS;
        int rows = min(XW_ROWS, N_NODES - rbase);
        int total = rows * F_IN;                     // multiple of 4
        const float4* gx4 = (const float4*)(x + (long)rbase * F_IN);
        for (int i4 = t; i4 < (total >> 2); i4 += BF_B) {
            float4 v = gx4[i4];                      // coalesced
            int i = i4 << 2;
            int r = i / F_IN;
            int k = i - r * F_IN;
            __half2* p = xs + r * XW_S2 + (k >> 1);
            p[0] = __floats2half2_rn(v.x, v.y);
            p[1] = __floats2half2_rn(v.z, v.w);
        }
        __syncthreads();
        int r = t & (XW_ROWS - 1);
        int colbase = __builtin_amdgcn_readfirstlane((t >> 8) << 3);
        if (r < rows) {
            const float* Wp = W + colbase;
            float acc[8];
#pragma unroll
            for (int j = 0; j < 8; j++) acc[j] = 0.f;
            const __half2* xr = xs + r * XW_S2;
#pragma unroll 5
            for (int k2 = 0; k2 < F_IN / 2; k2++) {
                float2 xv = __half22float2(xr[k2]);  // 1 ds_read_b32 / 16 FMA
#pragma unroll
                for (int j = 0; j < 8; j++)
                    acc[j] = fmaf(xv.y, Wp[(2 * k2 + 1) * F_H + j],
                                  fmaf(xv.x, Wp[(2 * k2) * F_H + j], acc[j]));
            }
            float4* dst4 = (float4*)(h2f + (long)(rbase + r) * F_H + colbase);
            dst4[0] = make_float4(acc[0], acc[1], acc[2], acc[3]);
            dst4[1] = make_float4(acc[4], acc[5], acc[6], acc[7]);
        }
        __syncthreads();
    }
}

// ---------------------------------------------- per-bucket: degree histogram ->
// dinv per row -> h2(fp16) = h2f * dinv (row-major, verified round-2/4 body);
// block 0 also writes the all-zero pad row at index ZROW.
__global__ __launch_bounds__(256) void scale_kernel(
        const int* __restrict__ blen, const unsigned* __restrict__ packed,
        const float* __restrict__ h2f, __half* __restrict__ h2) {
    __shared__ int cnt[BKT_C];
    __shared__ float sdv[BKT_C];
    int t = threadIdx.x;
    int b = blockIdx.x;
    if (t < BKT_C) cnt[t] = 0;
    __syncthreads();
    int beg = b * BKT_CAP, end = beg + blen[b];
    for (int i = beg + t; i < end; i += 256)
        atomicAdd(&cnt[(packed[i] >> 17) & (BKT_C - 1)], 1);
    __syncthreads();
    if (t < BKT_C) sdv[t] = rsqrtf((float)cnt[t] + 1.0f);
    __syncthreads();
    int rbase = b << BKT_SHIFT;
    int rows = min(BKT_C, N_NODES - rbase);
    const float4* src4 = (const float4*)(h2f + (long)rbase * F_H);
    float2* dst2 = (float2*)h2;                      // 4 halves per float2 slot
    if (b == 0 && t < 8)                             // zero pad row (64 B)
        dst2[(long)ZROW * 8 + t] = make_float2(0.f, 0.f);
    for (int i4 = t; i4 < rows * 8; i4 += 256) {     // rows * 32 floats / 4
        float4 v = src4[i4];                         // coalesced 16 B
        float dv = sdv[i4 >> 3];
        float2 o;
        __half2* oh = (__half2*)&o;
        oh[0] = __floats2half2_rn(v.x * dv, v.y * dv);
        oh[1] = __floats2half2_rn(v.z * dv, v.w * dv);
        dst2[(long)rbase * 8 + i4] = o;              // coalesced 8 B
    }
}

// ---------------------------------------------- per-bucket: LDS counting sort
// into x8-PADDED segments (pad slots = ZROW) -> full-batch gathers, no tail
// (r8 timed-best body) -> fused MLP + log_softmax
__global__ __launch_bounds__(AG_B) void agg_kernel(
        const int* __restrict__ blen, const unsigned* __restrict__ packed,
        const __half* __restrict__ h2,
        const float* __restrict__ bc,
        const float* __restrict__ W1, const float* __restrict__ b1,
        const float* __restrict__ W2, const float* __restrict__ b2,
        const float* __restrict__ W3, const float* __restrict__ b3,
        float* __restrict__ out) {
    __shared__ float accL[BKT_C * 33];           // 16.9 KB; written once per node
    __shared__ int esrc[AG_ESRC];                // 12.8 KB padded node-sorted src
    __shared__ int cnt[BKT_C];
    __shared__ int pstart[BKT_C];                // padded segment start per node
    __shared__ int wsum;
    __shared__ int ptotT;                        // total padded entries
    __shared__ float sbc[32], sW1[512], sb1[16], sW2[128], sb2[8], sW3[80], sb3[10];
    int t = threadIdx.x;
    if (t < 32) sbc[t] = bc[t];
    if (t < 512) sW1[t] = W1[t];
    if (t < 16) sb1[t] = b1[t];
    if (t < 128) sW2[t] = W2[t];
    if (t < 8) sb2[t] = b2[t];
    if (t < 80) sW3[t] = W3[t];
    if (t < 10) sb3[t] = b3[t];

    int b = blockIdx.x;
    int beg = b * BKT_CAP;
    int cnum = blen[b];                          // <= 2210 guaranteed
    if (t < BKT_C) cnt[t] = 0;
    __syncthreads();
    unsigned pk[AG_EPT]; int pos[AG_EPT];
#pragma unroll
    for (int k = 0; k < AG_EPT; k++) {
        int idx = t + k * AG_B;                  // coalesced
        pk[k] = 0xFFFFFFFFu;
        if (idx < cnum) {
            unsigned p = packed[beg + idx];
            pk[k] = p;
            pos[k] = atomicAdd(&cnt[(p >> 17) & (BKT_C - 1)], 1);
        }
    }
    __syncthreads();
    // inclusive scan of PADDED counts ((cnt+7)&~7) -> pstart per node
    {
        int lane = t & 63;
        int v = 0;
        if (t < BKT_C) {
            v = (cnt[t] + 7) & ~7;
#pragma unroll
            for (int off = 1; off < 64; off <<= 1) {
                int xx = __shfl_up(v, off, 64);
                if (lane >= off) v += xx;
            }
            if (t == 63) wsum = v;
        }
        __syncthreads();
        if (t < BKT_C) {
            if (t >= 64) v += wsum;
            pstart[t] = v - ((cnt[t] + 7) & ~7);
            if (t == BKT_C - 1) ptotT = v;
        }
    }
    __syncthreads();
    // pre-fill pad slots with the zero-row id, then scatter real edges
    for (int i = t; i < ptotT; i += AG_B) esrc[i] = ZROW;
    __syncthreads();
#pragma unroll
    for (int k = 0; k < AG_EPT; k++) {
        if (pk[k] != 0xFFFFFFFFu) {
            int lid = (pk[k] >> 17) & (BKT_C - 1);
            esrc[pstart[lid] + pos[k]] = (int)(pk[k] & 0x1FFFF);
        }
    }
    __syncthreads();
    // gather: group g (= t>>2) owns node g; lane l (= t&3) owns cols 8l..8l+7
    // (16 B -> 4 lanes cover one 64 B line per edge). Segment length is a
    // multiple of 8 -> every iteration issues 8 independent loads (pad slots
    // hit the L1-resident zero row and add exact +0).
    {
        int g = t >> 2, l = t & 3;
        const float4* h2o = (const float4*)h2;   // row = 4 float4 (8 halfs each)
        int e = pstart[g];
        int eend = e + ((cnt[g] + 7) & ~7);
        float a0 = 0.f, a1 = 0.f, a2 = 0.f, a3 = 0.f;
        float a4 = 0.f, a5 = 0.f, a6 = 0.f, a7 = 0.f;
        for (; e < eend; e += 8) {               // 8 independent 16 B gathers
            int s0 = esrc[e], s1 = esrc[e+1], s2 = esrc[e+2], s3 = esrc[e+3];
            int s4 = esrc[e+4], s5 = esrc[e+5], s6 = esrc[e+6], s7 = esrc[e+7];
            float4 q0 = h2o[s0 * 4 + l];
            float4 q1 = h2o[s1 * 4 + l];
            float4 q2 = h2o[s2 * 4 + l];
            float4 q3 = h2o[s3 * 4 + l];
            float4 q4 = h2o[s4 * 4 + l];
            float4 q5 = h2o[s5 * 4 + l];
            float4 q6 = h2o[s6 * 4 + l];
            float4 q7 = h2o[s7 * 4 + l];
#pragma unroll
            for (int u = 0; u < 8; u++) {
                float4 q = (u == 0) ? q0 : (u == 1) ? q1 : (u == 2) ? q2 :
                           (u == 3) ? q3 : (u == 4) ? q4 : (u == 5) ? q5 :
                           (u == 6) ? q6 : q7;
                const __half2* hp = (const __half2*)&q;
                float2 f0 = __half22float2(hp[0]);
                float2 f1 = __half22float2(hp[1]);
                float2 f2 = __half22float2(hp[2]);
                float2 f3 = __half22float2(hp[3]);
                a0 += f0.x; a1 += f0.y; a2 += f1.x; a3 += f1.y;
                a4 += f2.x; a5 += f2.y; a6 += f3.x; a7 += f3.y;
            }
        }
        float* ap = accL + g * 33 + 8 * l;
        ap[0] = a0; ap[1] = a1; ap[2] = a2; ap[3] = a3;
        ap[4] = a4; ap[5] = a5; ap[6] = a6; ap[7] = a7;
    }
    __syncthreads();

    // epilogue: threads 0..127 each finish one node; dinv[dst] from the local
    // histogram (cnt[t] == full in-degree of node n)
    int n = (b << BKT_SHIFT) + t;
    if (t < BKT_C && n < N_NODES) {
        float dv = rsqrtf((float)cnt[t] + 1.0f);
        const __half2* h2v = (const __half2*)h2;
        float a[32];
#pragma unroll
        for (int q = 0; q < 16; q++) {
            float2 hv = __half22float2(h2v[n * 16 + q]);   // self-loop (pre-scaled)
            a[2*q]   = fmaxf((accL[t * 33 + 2*q]   + hv.x) * dv + sbc[2*q],   0.f);
            a[2*q+1] = fmaxf((accL[t * 33 + 2*q+1] + hv.y) * dv + sbc[2*q+1], 0.f);
        }
        float t1[16];
#pragma unroll
        for (int j = 0; j < 16; j++) {
            float s = sb1[j];
            for (int k = 0; k < 32; k++) s += a[k] * sW1[k * 16 + j];
            t1[j] = fmaxf(s, 0.f);
        }
        float t2[8];
#pragma unroll
        for (int j = 0; j < 8; j++) {
            float s = sb2[j];
            for (int k = 0; k < 16; k++) s += t1[k] * sW2[k * 8 + j];
            t2[j] = fmaxf(s, 0.f);
        }
        float t3[10];
#pragma unroll
        for (int j = 0; j < 10; j++) {
            float s = sb3[j];
            for (int k = 0; k < 8; k++) s += t2[k] * sW3[k * 10 + j];
            t3[j] = s;
        }
        float m = t3[0];
#pragma unroll
        for (int j = 1; j < 10; j++) m = fmaxf(m, t3[j]);
        float se = 0.f;
#pragma unroll
        for (int j = 0; j < 10; j++) se += expf(t3[j] - m);
        float lse = logf(se) + m;
        float* op = out + (long)n * 10;
#pragma unroll
        for (int j = 0; j < 10; j++) op[j] = t3[j] - lse;
    }
}

extern "C" void kernel_launch(void* const* d_in, const int* in_sizes, int n_in,
                              void* d_out, int out_size, void* d_ws, size_t ws_size,
                              hipStream_t stream) {
    const float* x  = (const float*)d_in[0];
    const int*   ei = (const int*)d_in[1];  // [2, E] int32
    const float* Wc = (const float*)d_in[3];
    const float* bc = (const float*)d_in[4];
    const float* W1 = (const float*)d_in[5];
    const float* b1 = (const float*)d_in[6];
    const float* W2 = (const float*)d_in[7];
    const float* b2 = (const float*)d_in[8];
    const float* W3 = (const float*)d_in[9];
    const float* b3 = (const float*)d_in[10];
    float* out = (float*)d_out;

    // h2 has ONE extra zero row (index N_NODES) for gather padding
    __half*   h2      = (__half*)d_ws;                          // (N+1)*32 fp16
    unsigned* packed  = (unsigned*)((char*)d_ws
                         + (long)(N_NODES + 1) * F_H * 2);      // NBK*CAP (8 MB)
    float*    h2f     = (float*)(packed + (long)NBK * BKT_CAP); // N*32 fp32 (12.8 MB)
    int*      gcursor = (int*)(h2f + (long)N_NODES * F_H);      // NBK
    int*      xwctr   = gcursor + NBK;                          // 1 (steal counter)

    const int* srcp = ei;
    const int* dstp = ei + N_EDGES;

    hipMemsetAsync(gcursor, 0, (NBK + 1) * sizeof(int), stream);
    fused1_kernel<<<FUSE_GRID, BF_B, 0, stream>>>(srcp, dstp, gcursor, xwctr,
                                                  packed, x, Wc, h2f);
    scale_kernel<<<NBK, 256, 0, stream>>>(gcursor, packed, h2f, h2);
    agg_kernel<<<NBK, AG_B, 0, stream>>>(gcursor, packed, h2, bc, W1, b1,
                                         W2, b2, W3, b3, out);
}